// Round 3
// baseline (136.027 us; speedup 1.0000x reference)
//
#include <hip/hip_runtime.h>

// x (8192,64) f32, x_var (8192,64) f32, proto_mean (19,10,64) f32,
// proto_var (19,10,64) f32  ->  out (8192,19,10) f32.
//
// out[n,cm] = -1/128 * ( sum_k (pm-x)^2/(xv+pv) + ln prod_k (xv+pv) )
//
// Mapping: lane <-> cm (190 cms -> 3 waves, 2 idle lanes). Each lane keeps
// its prototype pm[64]/pv[64] in VGPRs, loaded ONCE per block, reused for
// all rows. Row data x[n][*], xv[n][*] is wave-uniform -> scalar s_load
// broadcast (1 SGPR operand per VALU op). Stores: lane<->cm is the fast
// output axis -> fully coalesced lines (round-2 write amp was 5x).
// Grid 1024 x 192thr x 8 rows = exactly 4 blocks/CU, 12 waves/CU.
#define NROWS 8192
#define KDIM  64
#define CMDIM 190
#define RPB   8                     // rows per block

__global__ __launch_bounds__(192, 3)   // cap VGPR ~170 -> 3 waves/SIMD resident
void probproto_kernel(const float* __restrict__ x,
                      const float* __restrict__ xv,
                      const float* __restrict__ pm,
                      const float* __restrict__ pv,
                      float* __restrict__ out)
{
    const int t    = threadIdx.x;
    const int cm   = (t >> 6) * 64 + (t & 63);      // 0..191
    const int cmc  = cm < CMDIM ? cm : CMDIM - 1;   // clamp for loads

    // ---- per-lane prototype registers: loaded once, reused for 8 rows ----
    float pmr[KDIM], pvr[KDIM];
    {
        const float4* pm4 = (const float4*)(pm + (size_t)cmc * KDIM);
        const float4* pv4 = (const float4*)(pv + (size_t)cmc * KDIM);
        #pragma unroll
        for (int i = 0; i < KDIM / 4; ++i) {
            float4 a = pm4[i], b = pv4[i];
            pmr[4*i+0] = a.x; pmr[4*i+1] = a.y; pmr[4*i+2] = a.z; pmr[4*i+3] = a.w;
            pvr[4*i+0] = b.x; pvr[4*i+1] = b.y; pvr[4*i+2] = b.z; pvr[4*i+3] = b.w;
        }
    }

    const int n0 = blockIdx.x * RPB;

    for (int r = 0; r < RPB; ++r) {
        const int n = n0 + r;
        const float* xrow = x  + (size_t)n * KDIM;  // wave-uniform -> s_load
        const float* vrow = xv + (size_t)n * KDIM;  // wave-uniform -> s_load

        float q[4] = {0.f, 0.f, 0.f, 0.f};   // 4 independent d^2/v chains
        float accL = 0.f;
        #pragma unroll
        for (int kc = 0; kc < 4; ++kc) {
            float p[4] = {1.f, 1.f, 1.f, 1.f};  // product chains; v in [1,2),
            #pragma unroll                       // 16-chunk < 2^16: no overflow
            for (int k8 = 0; k8 < 16; ++k8) {
                int k = kc * 16 + k8;
                float v = vrow[k] + pvr[k];      // SGPR + VGPR
                float d = xrow[k] - pmr[k];      // SGPR - VGPR
                q[k8 & 3] = fmaf(d * d, __builtin_amdgcn_rcpf(v), q[k8 & 3]);
                p[k8 & 3] *= v;
            }
            accL += __log2f((p[0] * p[1]) * (p[2] * p[3]));  // 1 log / 16 k
        }
        float res = -(((q[0] + q[1]) + (q[2] + q[3]))
                      + 0.69314718055994531f * accL) * (1.0f / 128.0f);
        if (cm < CMDIM)
            out[(size_t)n * CMDIM + cm] = res;   // coalesced: lane = fast axis
    }
}

extern "C" void kernel_launch(void* const* d_in, const int* in_sizes, int n_in,
                              void* d_out, int out_size, void* d_ws, size_t ws_size,
                              hipStream_t stream) {
    const float* x  = (const float*)d_in[0];
    const float* xv = (const float*)d_in[1];
    const float* pm = (const float*)d_in[2];
    const float* pv = (const float*)d_in[3];
    float* out = (float*)d_out;

    probproto_kernel<<<NROWS / RPB, 192, 0, stream>>>(x, xv, pm, pv, out);
}

// Round 4
// 97.714 us; speedup vs baseline: 1.3921x; 1.3921x over previous
//
#include <hip/hip_runtime.h>

// x (8192,64) f32, x_var (8192,64) f32, proto_mean (19,10,64) f32,
// proto_var (19,10,64) f32  ->  out (8192,19,10) f32.
//
// out[n,cm] = -1/128 * ( sum_k (pm-x)^2/(xv+pv) + ln prod_k (xv+pv) )
//
// Round-3 failure: 128 floats of per-lane proto state -> compiler capped
// VGPRs at 84 (its ~6-wave heuristic) and spilled the arrays to scratch
// (FETCH 100MB / WRITE 55MB of scratch traffic). Fix: chunk K into 4x16 so
// live per-lane state is ~60 floats -- no spill possible.
//
// Mapping: lane <-> cm (t==cm, 190 of 192 active). Per k-chunk: proto chunk
// (32 VGPRs) loaded once, reused across 4 rows; row x/xv chunks are
// wave-uniform -> scalar s_load broadcast. Stores coalesced (cm fast axis).
#define NROWS 8192
#define KDIM  64
#define CMDIM 190
#define RPB   4        // rows per block -> 2048 blocks, ~6 waves/SIMD
#define KC    16       // k per chunk; product of 16 v in [1,2) < 2^16

__global__ __launch_bounds__(192)
void probproto_kernel(const float* __restrict__ x,
                      const float* __restrict__ xv,
                      const float* __restrict__ pm,
                      const float* __restrict__ pv,
                      float* __restrict__ out)
{
    const int t  = threadIdx.x;                  // 0..191, t == cm
    const int cm = t < CMDIM ? t : CMDIM - 1;    // clamp for loads
    const int n0 = blockIdx.x * RPB;

    float accQ[RPB] = {0.f, 0.f, 0.f, 0.f};
    float accL[RPB] = {0.f, 0.f, 0.f, 0.f};

    #pragma unroll
    for (int c = 0; c < KDIM / KC; ++c) {
        // ---- proto chunk -> 32 VGPRs (reused across RPB rows) ----
        float pmc[KC], pvc[KC];
        const float4* pm4 = (const float4*)(pm + (size_t)cm * KDIM + c * KC);
        const float4* pv4 = (const float4*)(pv + (size_t)cm * KDIM + c * KC);
        #pragma unroll
        for (int i = 0; i < KC / 4; ++i) {
            float4 a = pm4[i], b = pv4[i];
            pmc[4*i+0] = a.x; pmc[4*i+1] = a.y; pmc[4*i+2] = a.z; pmc[4*i+3] = a.w;
            pvc[4*i+0] = b.x; pvc[4*i+1] = b.y; pvc[4*i+2] = b.z; pvc[4*i+3] = b.w;
        }

        #pragma unroll
        for (int r = 0; r < RPB; ++r) {
            // wave-uniform addresses -> scalar loads (broadcast)
            const float* xrow = x  + (size_t)(n0 + r) * KDIM + c * KC;
            const float* vrow = xv + (size_t)(n0 + r) * KDIM + c * KC;

            float q0 = 0.f, q1 = 0.f, q2 = 0.f, q3 = 0.f;   // 4 indep chains
            float p0 = 1.f, p1 = 1.f, p2 = 1.f, p3 = 1.f;
            #pragma unroll
            for (int k = 0; k < KC; k += 4) {
                float v0 = vrow[k+0] + pvc[k+0], d0 = xrow[k+0] - pmc[k+0];
                float v1 = vrow[k+1] + pvc[k+1], d1 = xrow[k+1] - pmc[k+1];
                float v2 = vrow[k+2] + pvc[k+2], d2 = xrow[k+2] - pmc[k+2];
                float v3 = vrow[k+3] + pvc[k+3], d3 = xrow[k+3] - pmc[k+3];
                q0 = fmaf(d0 * d0, __builtin_amdgcn_rcpf(v0), q0);
                q1 = fmaf(d1 * d1, __builtin_amdgcn_rcpf(v1), q1);
                q2 = fmaf(d2 * d2, __builtin_amdgcn_rcpf(v2), q2);
                q3 = fmaf(d3 * d3, __builtin_amdgcn_rcpf(v3), q3);
                p0 *= v0; p1 *= v1; p2 *= v2; p3 *= v3;
            }
            accQ[r] += (q0 + q1) + (q2 + q3);
            accL[r] += __log2f((p0 * p1) * (p2 * p3));   // 1 log per 16 k
        }
    }

    #pragma unroll
    for (int r = 0; r < RPB; ++r) {
        float res = -(accQ[r] + 0.69314718055994531f * accL[r]) * (1.0f / 128.0f);
        if (t < CMDIM)
            out[(size_t)(n0 + r) * CMDIM + t] = res;     // coalesced
    }
}

extern "C" void kernel_launch(void* const* d_in, const int* in_sizes, int n_in,
                              void* d_out, int out_size, void* d_ws, size_t ws_size,
                              hipStream_t stream) {
    const float* x  = (const float*)d_in[0];
    const float* xv = (const float*)d_in[1];
    const float* pm = (const float*)d_in[2];
    const float* pv = (const float*)d_in[3];
    float* out = (float*)d_out;

    probproto_kernel<<<NROWS / RPB, 192, 0, stream>>>(x, xv, pm, pv, out);
}

// Round 5
// 92.539 us; speedup vs baseline: 1.4699x; 1.0559x over previous
//
#include <hip/hip_runtime.h>

// x (8192,64) f32, x_var (8192,64) f32, proto_mean (19,10,64) f32,
// proto_var (19,10,64) f32  ->  out (8192,19,10) f32.
//
// out[n,cm] = -1/128 * ( sum_k (pm-x)^2/(xv+pv) + ln prod_k (xv+pv) )
//
// Mapping: lane <-> row. Each lane loads its x/xv row ONCE into 128 VGPRs
// and reuses it across 5 cm's. Proto addresses are wave-uniform -> s_load
// broadcast (scalar cache; same stream for all waves). 38 cm-tiles x 128
// row-tiles = 4864 one-wave blocks (~4.8 waves/SIMD launched).
//
// KEY FIX vs rounds 2/3: __launch_bounds__'s 2nd arg is only a MINIMUM-waves
// guarantee -- the backend still targeted 6 waves/EU (84 VGPR) and spilled
// the row arrays to scratch (round 3: FETCH 100 MB of scratch traffic).
// amdgpu_waves_per_eu(3,3) pins min=max -> 168-VGPR budget, no spill
// incentive. Need ~158.
#define NROWS 8192
#define KDIM  64
#define CMDIM 190
#define CMT   5       // cm per wave
#define NCT   38      // cm tiles (grid.x), 38*5 = 190

__global__ __launch_bounds__(64)
__attribute__((amdgpu_waves_per_eu(3, 3)))
void probproto_kernel(const float* __restrict__ x,
                      const float* __restrict__ xv,
                      const float* __restrict__ pm,
                      const float* __restrict__ pv,
                      float* __restrict__ out)
{
    const int lane = threadIdx.x;
    const int ct   = blockIdx.x;                 // 0..37
    const int n    = blockIdx.y * 64 + lane;     // global row

    // ---- this lane's full row of x and x_var -> 128 VGPRs, loaded once ----
    float xr[KDIM], vr[KDIM];
    const float4* xp = (const float4*)(x  + (size_t)n * KDIM);
    const float4* vp = (const float4*)(xv + (size_t)n * KDIM);
    #pragma unroll
    for (int i = 0; i < KDIM / 4; ++i) {
        float4 a = xp[i], b = vp[i];
        xr[4*i+0] = a.x; xr[4*i+1] = a.y; xr[4*i+2] = a.z; xr[4*i+3] = a.w;
        vr[4*i+0] = b.x; vr[4*i+1] = b.y; vr[4*i+2] = b.z; vr[4*i+3] = b.w;
    }

    float* orow = out + (size_t)n * CMDIM + ct * CMT;

    #pragma unroll 1                     // keep j rolled: small I-cache body,
    for (int j = 0; j < CMT; ++j) {      // sequential 512B proto s_load bursts
        const float* pmr = pm + (size_t)(ct * CMT + j) * KDIM;  // uniform -> s_load
        const float* pvr = pv + (size_t)(ct * CMT + j) * KDIM;

        float q0 = 0.f, q1 = 0.f, q2 = 0.f, q3 = 0.f;  // 4 indep rcp-fma chains
        float accL = 0.f;
        #pragma unroll
        for (int kc = 0; kc < 4; ++kc) {
            float p0 = 1.f, p1 = 1.f, p2 = 1.f, p3 = 1.f;  // v in [1,2):
            #pragma unroll                                  // 16-chunk < 2^16
            for (int k4 = 0; k4 < 4; ++k4) {
                int k = kc * 16 + k4 * 4;
                float v0 = vr[k+0] + pvr[k+0], d0 = pmr[k+0] - xr[k+0];
                float v1 = vr[k+1] + pvr[k+1], d1 = pmr[k+1] - xr[k+1];
                float v2 = vr[k+2] + pvr[k+2], d2 = pmr[k+2] - xr[k+2];
                float v3 = vr[k+3] + pvr[k+3], d3 = pmr[k+3] - xr[k+3];
                q0 = fmaf(d0 * d0, __builtin_amdgcn_rcpf(v0), q0);
                q1 = fmaf(d1 * d1, __builtin_amdgcn_rcpf(v1), q1);
                q2 = fmaf(d2 * d2, __builtin_amdgcn_rcpf(v2), q2);
                q3 = fmaf(d3 * d3, __builtin_amdgcn_rcpf(v3), q3);
                p0 *= v0; p1 *= v1; p2 *= v2; p3 *= v3;
            }
            accL += __log2f((p0 * p1) * (p2 * p3));   // 1 log per 16 k
        }
        orow[j] = -(((q0 + q1) + (q2 + q3))
                    + 0.69314718055994531f * accL) * (1.0f / 128.0f);
    }
}

extern "C" void kernel_launch(void* const* d_in, const int* in_sizes, int n_in,
                              void* d_out, int out_size, void* d_ws, size_t ws_size,
                              hipStream_t stream) {
    const float* x  = (const float*)d_in[0];
    const float* xv = (const float*)d_in[1];
    const float* pm = (const float*)d_in[2];
    const float* pv = (const float*)d_in[3];
    float* out = (float*)d_out;

    dim3 grid(NCT, NROWS / 64);   // 38 x 128 one-wave blocks
    probproto_kernel<<<grid, 64, 0, stream>>>(x, xv, pm, pv, out);
}